// Round 15
// baseline (845.109 us; speedup 1.0000x reference)
//
#include <hip/hip_runtime.h>
#include <hip/hip_bf16.h>

typedef unsigned short u16;
typedef unsigned int u32;
typedef __bf16 bf16x8 __attribute__((ext_vector_type(8)));
typedef float f32x4 __attribute__((ext_vector_type(4)));

#define NB 32
#define NT 1024
#define ND 192
#define NCH 768
#define NOUT 512

__device__ __forceinline__ float bf2f(u16 x) { return __uint_as_float(((u32)x) << 16); }
__device__ __forceinline__ u16 f2bf(float f) {
    u32 u = __float_as_uint(f);
    return (u16)((u + 0x7fffu + ((u >> 16) & 1u)) >> 16);
}
__device__ __forceinline__ float tanh_fast(float x) {
    float e = __expf(2.f * x);
    return 1.f - 2.f / (e + 1.f);
}
// bijective XCD chunking (m204)
__device__ __forceinline__ int xcd_swz(int bx, int nwg) {
    int q = nwg >> 3, r = nwg & 7;
    int xcd = bx & 7, idx = bx >> 3;
    return (xcd < r ? xcd * (q + 1) : r * (q + 1) + (xcd - r) * q) + idx;
}
// async global->LDS, 16B per lane, linear dest (wave base + lane*16)
__device__ __forceinline__ void gl_lds16(const u16* g, u16* l) {
    __builtin_amdgcn_global_load_lds(
        (const __attribute__((address_space(1))) void*)g,
        (__attribute__((address_space(3))) void*)l, 16, 0, 0);
}

__constant__ int NODE_IDX[3][4] = {{0, 0, 0, 0}, {1, 4, 0, 0}, {2, 5, 3, 6}};

// ---------- f32 -> bf16 pack (8 elems/thread) ----------
__global__ void cvt8(const float* __restrict__ in, u16* __restrict__ out, int n8) {
    int i = blockIdx.x * 256 + threadIdx.x;
    if (i >= n8) return;
    const float4* p = (const float4*)in + 2 * (size_t)i;
    float4 a = p[0], c = p[1];
    uint4 o;
    o.x = f2bf(a.x) | ((u32)f2bf(a.y) << 16);
    o.y = f2bf(a.z) | ((u32)f2bf(a.w) << 16);
    o.z = f2bf(c.x) | ((u32)f2bf(c.y) << 16);
    o.w = f2bf(c.z) | ((u32)f2bf(c.w) << 16);
    ((uint4*)out)[i] = o;
}

// ---------- W1 (28,768,192,5) f32 -> frag layout [nb][kkb 30][cob 48][lane][8] bf16 ----------
__global__ __launch_bounds__(256) void w1fk(const float* __restrict__ W1, u16* __restrict__ W1f) {
    __shared__ u16 ls[32][968];
    const int nb = blockIdx.x / 24;
    const int cot = blockIdx.x % 24;
    const float* src = W1 + ((size_t)nb * NCH + cot * 32) * (ND * 5);
    for (int idx = threadIdx.x; idx < 7680; idx += 256) {
        int e4 = idx * 4;
        int rowc = e4 / 960, col = e4 % 960;
        float4 v = *(const float4*)(src + (size_t)rowc * 960 + col);
        ls[rowc][col + 0] = f2bf(v.x);
        ls[rowc][col + 1] = f2bf(v.y);
        ls[rowc][col + 2] = f2bf(v.z);
        ls[rowc][col + 3] = f2bf(v.w);
    }
    __syncthreads();
    const int lane = threadIdx.x & 63, sub = threadIdx.x >> 6;
    const int g = lane >> 4, r = lane & 15;
    for (int it = 0; it < 15; ++it) {
        int fid = it * 4 + sub;
        int kkb = fid >> 1, cobl = fid & 1;
        u16 tmp[8];
#pragma unroll
        for (int e = 0; e < 8; ++e) {
            int kk = kkb * 32 + 8 * g + e;
            int ci = kk % 192, k = kk / 192;
            tmp[e] = ls[cobl * 16 + r][ci * 5 + k];
        }
        uint4 o;
        o.x = tmp[0] | ((u32)tmp[1] << 16);
        o.y = tmp[2] | ((u32)tmp[3] << 16);
        o.z = tmp[4] | ((u32)tmp[5] << 16);
        o.w = tmp[6] | ((u32)tmp[7] << 16);
        size_t off = (((size_t)nb * 30 + kkb) * 48 + cot * 2 + cobl) * 512 + lane * 8;
        *(uint4*)(W1f + off) = o;
    }
}

// ---------- W2 (28,192,768,3) f32 -> frag layout [nb][kkb 72][cob 12][lane][8] bf16 ----------
__global__ __launch_bounds__(256) void w2fk(const float* __restrict__ W2, u16* __restrict__ W2f) {
    __shared__ u16 ls[16][1160];
    const int ch = blockIdx.x & 1;
    const int t = blockIdx.x >> 1;
    const int nb = t / 12, cot = t % 12;
    const float* src = W2 + ((size_t)nb * ND + cot * 16) * (NCH * 3) + ch * 1152;
    for (int idx = threadIdx.x; idx < 4608; idx += 256) {
        int e4 = idx * 4;
        int rowc = e4 / 1152, col = e4 % 1152;
        float4 v = *(const float4*)(src + (size_t)rowc * (NCH * 3) + col);
        ls[rowc][col + 0] = f2bf(v.x);
        ls[rowc][col + 1] = f2bf(v.y);
        ls[rowc][col + 2] = f2bf(v.z);
        ls[rowc][col + 3] = f2bf(v.w);
    }
    __syncthreads();
    const int lane = threadIdx.x & 63, sub = threadIdx.x >> 6;
    const int g = lane >> 4, r = lane & 15;
    for (int it = 0; it < 9; ++it) {
        int fid = it * 4 + sub;
        int k = fid / 12, cib = fid % 12;
        int kkb = k * 24 + ch * 12 + cib;
        u16 tmp[8];
#pragma unroll
        for (int e = 0; e < 8; ++e) {
            int cl = cib * 32 + 8 * g + e;
            tmp[e] = ls[r][cl * 3 + k];
        }
        uint4 o;
        o.x = tmp[0] | ((u32)tmp[1] << 16);
        o.y = tmp[2] | ((u32)tmp[3] << 16);
        o.z = tmp[4] | ((u32)tmp[5] << 16);
        o.w = tmp[6] | ((u32)tmp[7] << 16);
        size_t off = (((size_t)nb * 72 + kkb) * 12 + cot) * 512 + lane * 8;
        *(uint4*)(W2f + off) = o;
    }
}

// ---------- conv1 MFMA: faithful m97 port. 128x128 tile, 4 waves 2x2 of 64x64 ----------
// A im2col STREAMED per-cib chunk (136x32, dbuf, source-swizzled global_load_lds);
// B streamed per-K-step (8KB frag chunks, dbuf); one barrier per step; 33KB LDS.
__global__ __launch_bounds__(256) void conv1m(
    const u16* __restrict__ bufb, const u16* __restrict__ dbufb, const u16* __restrict__ cbufb,
    const u16* __restrict__ W1f, const float* __restrict__ b1,
    u16* __restrict__ h, int lvl, int stage) {
    const int L = 512 >> lvl, nodes = 1 << lvl, Lout = L + 2;
    const int tid = threadIdx.x;
    const int cot = blockIdx.x % 6;
    const int mt = blockIdx.x / 6;
    const int z = blockIdx.z;
    const int g_node = z & (nodes - 1);
    const int br = z >> lvl;
    const int nb4 = NODE_IDX[lvl][g_node] * 4 + (stage ? 2 + br : br);

    const int r0 = mt * 128;
    const int b0 = r0 / Lout;
    const int t00 = r0 - b0 * Lout;
    const int s = Lout - t00;  // rows until batch boundary (may exceed 128)
    const int rowsValid0 = NB * Lout - r0;
    const int rowsValid = rowsValid0 < 128 ? rowsValid0 : 128;

    __shared__ u16 a_lds[2][136 * 32];  // 8.5 KB x2 : one cib chunk, 136 rows x 32 ci
    __shared__ u16 b_lds[2][4096];      // 8 KB x2   : one K-step B chunk (8 cob x 512)

    const int lane = tid & 63, w = tid >> 6;
    const int wrow = w >> 1, wcol = w & 1;
    const int lr = lane & 15, lg = lane >> 4;

    // B staging: kkb = k*6+cib, 8KB contiguous per step
    const u16* wsrc = W1f + ((size_t)nb4 * 30 * 48 + cot * 8) * 512;
    auto stageB = [&](int st, int bufi) {
        const int cib = st / 5, k = st % 5;
        const int kkb = k * 6 + cib;
        const u16* gp = wsrc + (size_t)kkb * (48 * 512) + tid * 8;
        gl_lds16(gp, &b_lds[bufi][tid * 8]);
        gl_lds16(gp + 2048, &b_lds[bufi][tid * 8 + 2048]);
    };

    // A staging: 136 rows x 32 ci of cib chunk; source pre-swizzled so that
    // LDS slot (j, cp) holds global ci-chunk cp ^ ((j>>1)&3)  (rule #21)
    const u16* dcb = br ? cbufb : dbufb;
    const int slot = g_node + (br << lvl);
    auto stageA = [&](int cib, int bufi) {
#pragma unroll
        for (int inst = 0; inst < 3; ++inst) {
            if (inst == 2 && tid >= 32) continue;  // 544 units = 2*256 + 32
            int unit = inst * 256 + tid;
            int j = unit >> 2, cp = unit & 3;
            int gc = cp ^ ((j >> 1) & 3);
            int bb, u;
            if (j <= s + 3) { bb = b0; u = t00 - 3 + j; }
            else            { bb = b0 + 1; u = j - s - 7; }
            u = u < 0 ? 0 : (u > L - 1 ? L - 1 : u);
            if (bb > NB - 1) bb = NB - 1;
            const u16* p;
            if (stage == 0)
                p = bufb + ((size_t)bb * NT + slot + (size_t)u * (2 * nodes)) * ND;
            else
                p = dcb + (((size_t)g_node * NB + bb) * L + u) * (size_t)ND;
            gl_lds16(p + cib * 32 + gc * 8, &a_lds[bufi][unit * 8]);
        }
    };

    // prologue: chunk 0 + B step 0 + chunk 1, then full drain
    stageA(0, 0);
    stageB(0, 0);
    stageA(1, 1);
    __syncthreads();

    int rowb[4];
#pragma unroll
    for (int m = 0; m < 4; ++m) {
        int i = wrow * 64 + m * 16 + lr;
        rowb[m] = i + (i >= s ? 4 : 0);
    }

    f32x4 acc[4][4];
    f32x4 zz = {0.f, 0.f, 0.f, 0.f};
#pragma unroll
    for (int m = 0; m < 4; ++m)
#pragma unroll
        for (int n = 0; n < 4; ++n) acc[m][n] = zz;

#pragma unroll
    for (int st = 0; st < 30; ++st) {
        const int cib = st / 5, k = st % 5;
        // issue next-step B stage (lands by this step's barrier)
        if (st + 1 < 30) stageB(st + 1, (st + 1) & 1);
        // at each cib start (after the prologue's chunk 1), stage chunk cib+2... i.e. cib+1
        if (k == 0 && cib >= 1 && cib < 5) stageA(cib + 1, (cib + 1) & 1);
        bf16x8 Ar[4], Br[4];
#pragma unroll
        for (int m = 0; m < 4; ++m) {
            int r = rowb[m] + k;
            Ar[m] = *(const bf16x8*)(&a_lds[cib & 1][r * 32 + ((lg ^ ((r >> 1) & 3)) * 8)]);
        }
#pragma unroll
        for (int n = 0; n < 4; ++n)
            Br[n] = *(const bf16x8*)(&b_lds[st & 1][(wcol * 4 + n) * 512 + lane * 8]);
#pragma unroll
        for (int m = 0; m < 4; ++m)
#pragma unroll
            for (int n = 0; n < 4; ++n)
                acc[m][n] = __builtin_amdgcn_mfma_f32_16x16x32_bf16(
                    Ar[m], Br[n], acc[m][n], 0, 0, 0);
        if (st < 29) __syncthreads();
    }

    float bias[4];
    const float* bb1 = b1 + (size_t)nb4 * NCH + cot * 128 + wcol * 64 + lr;
#pragma unroll
    for (int n = 0; n < 4; ++n) bias[n] = bb1[n * 16];
    u16* hz = h + (size_t)z * NB * Lout * NCH;
#pragma unroll
    for (int m = 0; m < 4; ++m) {
#pragma unroll
        for (int rr = 0; rr < 4; ++rr) {
            int i = wrow * 64 + m * 16 + lg * 4 + rr;
            if (i < rowsValid) {
                int cross = (i >= s) ? 1 : 0;
                int bb = b0 + cross;
                int tt = cross ? i - s : t00 + i;
                u16* dst = hz + ((size_t)bb * Lout + tt) * NCH + cot * 128 + wcol * 64 + lr;
#pragma unroll
                for (int n = 0; n < 4; ++n) {
                    float v = acc[m][n][rr] + bias[n];
                    v = v > 0.f ? v : 0.01f * v;
                    dst[n * 16] = f2bf(v);
                }
            }
        }
    }
}

// ---------- conv2 MFMA: 128x192 block, 512 thr (2x4 waves of 64x48) ----------
// cc loop UNROLLED so the B/A ring indices are compile-time (rule #20)
__global__ __launch_bounds__(512) void conv2m(
    u16* __restrict__ bufb, u16* __restrict__ dbufb, u16* __restrict__ cbufb,
    const u16* __restrict__ W2f, const float* __restrict__ b2,
    const u16* __restrict__ h, int lvl, int stage) {
    const int L = 512 >> lvl, nodes = 1 << lvl, Lout = L + 2;
    const int tid = threadIdx.x;
    const int nM = (NB * L) >> 7;
    const int wg = xcd_swz(blockIdx.x, gridDim.x);
    const int z = wg / nM;
    const int mt = wg - z * nM;
    const int g_node = z & (nodes - 1);
    const int br = z >> lvl;
    const int nb4 = NODE_IDX[lvl][g_node] * 4 + (stage ? 2 + br : br);
    const int r0 = mt * 128;
    const int b = r0 >> (9 - lvl);
    const int t0 = r0 & (L - 1);

    __shared__ u16 xs[130 * 192];
    const u16* hz = h + ((size_t)z * NB + b) * Lout * NCH;

    const int lane = tid & 63, w = tid >> 6;
    const int wrow = w >> 2, wcol = w & 3;
    const int lr = lane & 15, lg = lane >> 4;
    const u16* wf = W2f + ((size_t)nb4 * 72 * 12 + wcol * 3) * 512 + lane * 8;

    auto kkb_of = [](int st) {
        int cc = st / 18, sp = st % 18;
        return (sp / 6) * 24 + cc * 6 + (sp % 6);
    };
    bf16x8 Bb[4][3], Ab[2][4];
    auto loadB = [&](bf16x8(&dst)[3], int st) {
        const size_t kb = (size_t)kkb_of(st) * 12 * 512;
#pragma unroll
        for (int n = 0; n < 3; ++n)
            dst[n] = *(const bf16x8*)(wf + kb + (size_t)n * 512);
    };
    auto loadA = [&](bf16x8(&dst)[4], int sp) {
        const int k = sp / 6, cj = sp % 6;
#pragma unroll
        for (int m = 0; m < 4; ++m) {
            int row = wrow * 64 + m * 16 + lr + k;
            dst[m] = *(const bf16x8*)(xs + row * 192 + ((cj * 32 + lg * 8) ^ ((row & 7) << 3)));
        }
    };
    loadB(Bb[0], 0);
    loadB(Bb[1], 1);
    loadB(Bb[2], 2);

    f32x4 acc[4][3];
    f32x4 zz = {0.f, 0.f, 0.f, 0.f};
#pragma unroll
    for (int m = 0; m < 4; ++m)
#pragma unroll
        for (int n = 0; n < 3; ++n) acc[m][n] = zz;

#pragma unroll
    for (int cc = 0; cc < 4; ++cc) {
        __syncthreads();
        for (int ch = tid; ch < 130 * 24; ch += 512) {
            int j = ch / 24, c8 = ch % 24;
            *(uint4*)(xs + j * 192 + ((c8 * 8) ^ ((j & 7) << 3))) =
                *(const uint4*)(hz + (size_t)(t0 + j) * NCH + cc * 192 + c8 * 8);
        }
        __syncthreads();
        loadA(Ab[0], 0);
#pragma unroll
        for (int sp = 0; sp < 18; ++sp) {
            int st = cc * 18 + sp;
            if (st + 3 < 72) loadB(Bb[(st + 3) & 3], st + 3);
            if (sp + 1 < 18) loadA(Ab[(sp + 1) & 1], sp + 1);
#pragma unroll
            for (int m = 0; m < 4; ++m)
#pragma unroll
                for (int n = 0; n < 3; ++n)
                    acc[m][n] = __builtin_amdgcn_mfma_f32_16x16x32_bf16(
                        Ab[sp & 1][m], Bb[st & 3][n], acc[m][n], 0, 0, 0);
        }
    }

    float bias[3];
    const float* bb2 = b2 + (size_t)nb4 * ND + wcol * 48 + lr;
#pragma unroll
    for (int n = 0; n < 3; ++n) bias[n] = bb2[n * 16];

    const int tstr = 2 * nodes;
    if (stage == 0) {
        const int mo = g_node + (br == 0 ? nodes : 0);
        const u16* mult = bufb + ((size_t)b * NT + mo) * ND;
        u16* dst = (br == 0 ? dbufb : cbufb) + ((size_t)g_node * NB + b) * (size_t)L * ND;
#pragma unroll
        for (int m = 0; m < 4; ++m) {
#pragma unroll
            for (int rr = 0; rr < 4; ++rr) {
                int i = wrow * 64 + m * 16 + lg * 4 + rr;
                int t = t0 + i;
#pragma unroll
                for (int n = 0; n < 3; ++n) {
                    int co = wcol * 48 + n * 16 + lr;
                    float v = tanh_fast(acc[m][n][rr] + bias[n]);
                    float mlt = bf2f(mult[(size_t)t * tstr * ND + co]);
                    dst[(size_t)t * ND + co] = f2bf(mlt * __expf(v));
                }
            }
        }
    } else {
        const u16* other = (br == 0 ? cbufb : dbufb) + ((size_t)g_node * NB + b) * (size_t)L * ND;
        const int to = g_node + (br ? nodes : 0);
        u16* dst = bufb + ((size_t)b * NT + to) * ND;
#pragma unroll
        for (int m = 0; m < 4; ++m) {
#pragma unroll
            for (int rr = 0; rr < 4; ++rr) {
                int i = wrow * 64 + m * 16 + lg * 4 + rr;
                int t = t0 + i;
#pragma unroll
                for (int n = 0; n < 3; ++n) {
                    int co = wcol * 48 + n * 16 + lr;
                    float v = tanh_fast(acc[m][n][rr] + bias[n]);
                    float o = bf2f(other[(size_t)t * ND + co]);
                    dst[(size_t)t * tstr * ND + co] = f2bf(br == 0 ? o + v : o - v);
                }
            }
        }
    }
}

// ---------- build in2T[b][d][t] = bf16(buf + x) transposed ----------
__global__ __launch_bounds__(256) void mkin2T(const u16* __restrict__ bufb,
                                              const float* __restrict__ x,
                                              u16* __restrict__ in2T) {
    __shared__ u16 ls[64][72];
    const int b = blockIdx.z, t0 = blockIdx.y * 64, d0 = blockIdx.x * 64;
    const int tid = threadIdx.x;
#pragma unroll
    for (int it = 0; it < 2; ++it) {
        int idx = tid + it * 256;
        int c8 = idx >> 6, row = idx & 63;
        size_t base = ((size_t)b * NT + t0 + row) * ND + d0 + c8 * 8;
        uint4 vb = *(const uint4*)(bufb + base);
        float4 x1 = *(const float4*)(x + base);
        float4 x2 = *(const float4*)(x + base + 4);
        const u16* vs = (const u16*)&vb;
        ls[c8 * 8 + 0][row] = f2bf(bf2f(vs[0]) + x1.x);
        ls[c8 * 8 + 1][row] = f2bf(bf2f(vs[1]) + x1.y);
        ls[c8 * 8 + 2][row] = f2bf(bf2f(vs[2]) + x1.z);
        ls[c8 * 8 + 3][row] = f2bf(bf2f(vs[3]) + x1.w);
        ls[c8 * 8 + 4][row] = f2bf(bf2f(vs[4]) + x2.x);
        ls[c8 * 8 + 5][row] = f2bf(bf2f(vs[5]) + x2.y);
        ls[c8 * 8 + 6][row] = f2bf(bf2f(vs[6]) + x2.z);
        ls[c8 * 8 + 7][row] = f2bf(bf2f(vs[7]) + x2.w);
    }
    __syncthreads();
#pragma unroll
    for (int it = 0; it < 2; ++it) {
        int idx = tid + it * 256;
        int dl = idx >> 3, t8 = idx & 7;
        uint4 v = *(uint4*)&ls[dl][t8 * 8];
        *(uint4*)(in2T + ((size_t)b * ND + d0 + dl) * NT + t0 + t8 * 8) = v;
    }
}

// ---------- projection MFMA: out[b][o][d] = sum_t Wp[o][t]*(buf+x)[t][d] ----------
__global__ __launch_bounds__(256) void projm(const u16* __restrict__ in2T,
                                             const u16* __restrict__ Wpb,
                                             float* __restrict__ out) {
    const int b = blockIdx.y, ot = blockIdx.x;
    const int tid = threadIdx.x, lane = tid & 63, w = tid >> 6;
    const int lr = lane & 15, lg = lane >> 4;
    const u16* ap = Wpb + ((size_t)(ot * 32 + lr)) * NT + lg * 8;
    const u16* bp = in2T + ((size_t)b * ND + w * 48 + lr) * NT + lg * 8;

    f32x4 acc[2][3];
    f32x4 zz = {0.f, 0.f, 0.f, 0.f};
#pragma unroll
    for (int m = 0; m < 2; ++m)
#pragma unroll
        for (int n = 0; n < 3; ++n) acc[m][n] = zz;

    auto loadA = [&](bf16x8(&dst)[2], int kkb) {
#pragma unroll
        for (int m = 0; m < 2; ++m)
            dst[m] = *(const bf16x8*)(ap + (size_t)m * 16 * NT + kkb * 32);
    };
    auto loadB = [&](bf16x8(&dst)[3], int kkb) {
#pragma unroll
        for (int n = 0; n < 3; ++n)
            dst[n] = *(const bf16x8*)(bp + (size_t)n * 16 * NT + kkb * 32);
    };
    auto domfma = [&](bf16x8(&A)[2], bf16x8(&B)[3]) {
#pragma unroll
        for (int m = 0; m < 2; ++m)
#pragma unroll
            for (int n = 0; n < 3; ++n)
                acc[m][n] = __builtin_amdgcn_mfma_f32_16x16x32_bf16(A[m], B[n], acc[m][n], 0, 0, 0);
    };

    bf16x8 Ab[2][2], Bb[3][3];
    loadA(Ab[0], 0);
    loadB(Bb[0], 0);
    loadB(Bb[1], 1);
#pragma unroll
    for (int sp = 0; sp < 32; ++sp) {
        if (sp + 2 < 32) loadB(Bb[(sp + 2) % 3], sp + 2);
        if (sp + 1 < 32) loadA(Ab[(sp + 1) & 1], sp + 1);
        domfma(Ab[sp & 1], Bb[sp % 3]);
    }

#pragma unroll
    for (int m = 0; m < 2; ++m)
#pragma unroll
        for (int rr = 0; rr < 4; ++rr) {
            int o = ot * 32 + m * 16 + lg * 4 + rr;
#pragma unroll
            for (int n = 0; n < 3; ++n) {
                int d = w * 48 + n * 16 + lr;
                out[((size_t)b * NOUT + o) * ND + d] = acc[m][n][rr];
            }
        }
}

extern "C" void kernel_launch(void* const* d_in, const int* in_sizes, int n_in,
                              void* d_out, int out_size, void* d_ws, size_t ws_size,
                              hipStream_t stream) {
    const float* x = (const float*)d_in[0];
    const float* W1 = (const float*)d_in[1];
    const float* b1 = (const float*)d_in[2];
    const float* W2 = (const float*)d_in[3];
    const float* b2 = (const float*)d_in[4];
    const float* Wp = (const float*)d_in[5];
    float* out = (float*)d_out;

    char* wsb = (char*)d_ws;
    size_t off = 0;
    auto carve = [&](size_t bytes) {
        void* p = wsb + off;
        off += (bytes + 255) & ~(size_t)255;
        return p;
    };
    const size_t w1f_e = (size_t)28 * 30 * 48 * 512;
    const size_t w2f_e = (size_t)28 * 72 * 12 * 512;
    const size_t wpb_e = (size_t)NOUT * NT;
    const size_t buf_e = (size_t)NB * NT * ND;
    const size_t dc_e = (size_t)NB * 512 * ND;
    const size_t h_e = (size_t)1040 * NB * NCH;
    const size_t i2_e = (size_t)NB * ND * NT;

    u16* W1f = (u16*)carve(sizeof(u16) * w1f_e);
    u16* W2f = (u16*)carve(sizeof(u16) * w2f_e);
    u16* Wpb = (u16*)carve(sizeof(u16) * wpb_e);
    u16* bufb = (u16*)carve(sizeof(u16) * buf_e);
    u16* dbufb = (u16*)carve(sizeof(u16) * dc_e);
    u16* cbufb = (u16*)carve(sizeof(u16) * dc_e);
    u16* h = (u16*)carve(sizeof(u16) * h_e);
    u16* in2T = (u16*)carve(sizeof(u16) * i2_e);
    if (off > ws_size) return;

    cvt8<<<(int)(buf_e / 8 / 256), 256, 0, stream>>>(x, bufb, (int)(buf_e / 8));
    cvt8<<<(int)(wpb_e / 8 / 256), 256, 0, stream>>>(Wp, Wpb, (int)(wpb_e / 8));
    w1fk<<<28 * 24, 256, 0, stream>>>(W1, W1f);
    w2fk<<<28 * 12 * 2, 256, 0, stream>>>(W2, W2f);

    for (int lvl = 0; lvl < 3; ++lvl) {
        int L = 512 >> lvl, nodes = 1 << lvl, Lout = L + 2;
        int mT1 = (NB * Lout + 127) / 128;
        int nM = NB * L / 128;
        dim3 g1(6 * mT1, 1, 2 * nodes);
        dim3 g2(nM * 2 * nodes);
        conv1m<<<g1, 256, 0, stream>>>(bufb, dbufb, cbufb, W1f, b1, h, lvl, 0);
        conv2m<<<g2, 512, 0, stream>>>(bufb, dbufb, cbufb, W2f, b2, h, lvl, 0);
        conv1m<<<g1, 256, 0, stream>>>(bufb, dbufb, cbufb, W1f, b1, h, lvl, 1);
        conv2m<<<g2, 512, 0, stream>>>(bufb, dbufb, cbufb, W2f, b2, h, lvl, 1);
    }
    mkin2T<<<dim3(3, 16, NB), 256, 0, stream>>>(bufb, x, in2T);
    projm<<<dim3(16, NB), 256, 0, stream>>>(in2T, Wpb, out);
}

// Round 16
// 771.273 us; speedup vs baseline: 1.0957x; 1.0957x over previous
//
#include <hip/hip_runtime.h>
#include <hip/hip_bf16.h>

typedef unsigned short u16;
typedef unsigned int u32;
typedef __bf16 bf16x8 __attribute__((ext_vector_type(8)));
typedef float f32x4 __attribute__((ext_vector_type(4)));

#define NB 32
#define NT 1024
#define ND 192
#define NCH 768
#define NOUT 512

__device__ __forceinline__ float bf2f(u16 x) { return __uint_as_float(((u32)x) << 16); }
__device__ __forceinline__ u16 f2bf(float f) {
    u32 u = __float_as_uint(f);
    return (u16)((u + 0x7fffu + ((u >> 16) & 1u)) >> 16);
}
__device__ __forceinline__ float tanh_fast(float x) {
    float e = __expf(2.f * x);
    return 1.f - 2.f / (e + 1.f);
}
// bijective XCD chunking (m204)
__device__ __forceinline__ int xcd_swz(int bx, int nwg) {
    int q = nwg >> 3, r = nwg & 7;
    int xcd = bx & 7, idx = bx >> 3;
    return (xcd < r ? xcd * (q + 1) : r * (q + 1) + (xcd - r) * q) + idx;
}

__constant__ int NODE_IDX[3][4] = {{0, 0, 0, 0}, {1, 4, 0, 0}, {2, 5, 3, 6}};

// ---------- f32 -> bf16 pack (8 elems/thread) ----------
__global__ void cvt8(const float* __restrict__ in, u16* __restrict__ out, int n8) {
    int i = blockIdx.x * 256 + threadIdx.x;
    if (i >= n8) return;
    const float4* p = (const float4*)in + 2 * (size_t)i;
    float4 a = p[0], c = p[1];
    uint4 o;
    o.x = f2bf(a.x) | ((u32)f2bf(a.y) << 16);
    o.y = f2bf(a.z) | ((u32)f2bf(a.w) << 16);
    o.z = f2bf(c.x) | ((u32)f2bf(c.y) << 16);
    o.w = f2bf(c.z) | ((u32)f2bf(c.w) << 16);
    ((uint4*)out)[i] = o;
}

// ---------- W1 (28,768,192,5) f32 -> frag layout [nb][kkb 30][cob 48][lane][8] bf16 ----------
__global__ __launch_bounds__(256) void w1fk(const float* __restrict__ W1, u16* __restrict__ W1f) {
    __shared__ u16 ls[32][968];
    const int nb = blockIdx.x / 24;
    const int cot = blockIdx.x % 24;
    const float* src = W1 + ((size_t)nb * NCH + cot * 32) * (ND * 5);
    for (int idx = threadIdx.x; idx < 7680; idx += 256) {
        int e4 = idx * 4;
        int rowc = e4 / 960, col = e4 % 960;
        float4 v = *(const float4*)(src + (size_t)rowc * 960 + col);
        ls[rowc][col + 0] = f2bf(v.x);
        ls[rowc][col + 1] = f2bf(v.y);
        ls[rowc][col + 2] = f2bf(v.z);
        ls[rowc][col + 3] = f2bf(v.w);
    }
    __syncthreads();
    const int lane = threadIdx.x & 63, sub = threadIdx.x >> 6;
    const int g = lane >> 4, r = lane & 15;
    for (int it = 0; it < 15; ++it) {
        int fid = it * 4 + sub;
        int kkb = fid >> 1, cobl = fid & 1;
        u16 tmp[8];
#pragma unroll
        for (int e = 0; e < 8; ++e) {
            int kk = kkb * 32 + 8 * g + e;
            int ci = kk % 192, k = kk / 192;
            tmp[e] = ls[cobl * 16 + r][ci * 5 + k];
        }
        uint4 o;
        o.x = tmp[0] | ((u32)tmp[1] << 16);
        o.y = tmp[2] | ((u32)tmp[3] << 16);
        o.z = tmp[4] | ((u32)tmp[5] << 16);
        o.w = tmp[6] | ((u32)tmp[7] << 16);
        size_t off = (((size_t)nb * 30 + kkb) * 48 + cot * 2 + cobl) * 512 + lane * 8;
        *(uint4*)(W1f + off) = o;
    }
}

// ---------- W2 (28,192,768,3) f32 -> frag layout [nb][kkb 72][cob 12][lane][8] bf16 ----------
__global__ __launch_bounds__(256) void w2fk(const float* __restrict__ W2, u16* __restrict__ W2f) {
    __shared__ u16 ls[16][1160];
    const int ch = blockIdx.x & 1;
    const int t = blockIdx.x >> 1;
    const int nb = t / 12, cot = t % 12;
    const float* src = W2 + ((size_t)nb * ND + cot * 16) * (NCH * 3) + ch * 1152;
    for (int idx = threadIdx.x; idx < 4608; idx += 256) {
        int e4 = idx * 4;
        int rowc = e4 / 1152, col = e4 % 1152;
        float4 v = *(const float4*)(src + (size_t)rowc * (NCH * 3) + col);
        ls[rowc][col + 0] = f2bf(v.x);
        ls[rowc][col + 1] = f2bf(v.y);
        ls[rowc][col + 2] = f2bf(v.z);
        ls[rowc][col + 3] = f2bf(v.w);
    }
    __syncthreads();
    const int lane = threadIdx.x & 63, sub = threadIdx.x >> 6;
    const int g = lane >> 4, r = lane & 15;
    for (int it = 0; it < 9; ++it) {
        int fid = it * 4 + sub;
        int k = fid / 12, cib = fid % 12;
        int kkb = k * 24 + ch * 12 + cib;
        u16 tmp[8];
#pragma unroll
        for (int e = 0; e < 8; ++e) {
            int cl = cib * 32 + 8 * g + e;
            tmp[e] = ls[r][cl * 3 + k];
        }
        uint4 o;
        o.x = tmp[0] | ((u32)tmp[1] << 16);
        o.y = tmp[2] | ((u32)tmp[3] << 16);
        o.z = tmp[4] | ((u32)tmp[5] << 16);
        o.w = tmp[6] | ((u32)tmp[7] << 16);
        size_t off = (((size_t)nb * 72 + kkb) * 12 + cot) * 512 + lane * 8;
        *(uint4*)(W2f + off) = o;
    }
}

// ---------- conv1 MFMA: M-tile 64, 2x2 waves of 32x64 (R4 optimum, best measured) ----------
// + primed B ping-pong (hides L2 latency under A staging) + precomputed A addrs
__global__ __launch_bounds__(256) void conv1m(
    const u16* __restrict__ bufb, const u16* __restrict__ dbufb, const u16* __restrict__ cbufb,
    const u16* __restrict__ W1f, const float* __restrict__ b1,
    u16* __restrict__ h, int lvl, int stage) {
    const int L = 512 >> lvl, nodes = 1 << lvl, Lout = L + 2;
    const int tid = threadIdx.x;
    const int mT1 = (NB * Lout + 63) / 64;
    const int wg = xcd_swz(blockIdx.x, gridDim.x);
    const int z = wg / (6 * mT1);
    const int rem = wg - z * 6 * mT1;
    const int mt = rem / 6;
    const int cot = rem % 6;
    const int g_node = z & (nodes - 1);
    const int br = z >> lvl;
    const int nb4 = NODE_IDX[lvl][g_node] * 4 + (stage ? 2 + br : br);

    const int r0 = mt * 64;
    const int b0 = r0 / Lout;
    const int t00 = r0 - b0 * Lout;
    const int s = Lout - t00;  // rows until batch boundary (may exceed 64)
    const int rowsValid0 = NB * Lout - r0;
    const int rowsValid = rowsValid0 < 64 ? rowsValid0 : 64;

    __shared__ u16 xs[72 * 192];  // 27.6 KB -> 5 blocks/CU

    const int lane = tid & 63, w = tid >> 6;
    const int wrow = w >> 1, wcol = w & 1;
    const int lr = lane & 15, lg = lane >> 4;
    const u16* wf = W1f + ((size_t)nb4 * 30 * 48 + cot * 8 + wcol * 4) * 512 + lane * 8;

    bf16x8 aE[2], bE[4], aO[2], bO[4];
    auto loadB = [&](bf16x8(&dst)[4], int step) {
#pragma unroll
        for (int n = 0; n < 4; ++n)
            dst[n] = *(const bf16x8*)(wf + ((size_t)step * 48 + n) * 512);
    };
    // prime BOTH ping-pong slots: their L2 latency hides under the A staging below
    loadB(bE, 0);
    loadB(bO, 1);

    const u16* dcb = br ? cbufb : dbufb;
    const int slot = g_node + (br << lvl);
    for (int ch = tid; ch < 72 * 24; ch += 256) {
        int j = ch / 24, c8 = ch % 24;
        int bb, u;
        if (j <= s + 3) { bb = b0; u = t00 - 3 + j; }
        else            { bb = b0 + 1; u = j - s - 7; }
        u = u < 0 ? 0 : (u > L - 1 ? L - 1 : u);
        if (bb > NB - 1) bb = NB - 1;
        const u16* p;
        if (stage == 0)
            p = bufb + ((size_t)bb * NT + slot + (size_t)u * (2 * nodes)) * ND + c8 * 8;
        else
            p = dcb + (((size_t)g_node * NB + bb) * L + u) * (size_t)ND + c8 * 8;
        *(uint4*)(xs + j * 192 + ((c8 * 8) ^ ((j & 7) << 3))) = *(const uint4*)p;
    }
    __syncthreads();

    int rowb[2];
#pragma unroll
    for (int m = 0; m < 2; ++m) {
        int i = wrow * 32 + m * 16 + lr;
        rowb[m] = i + (i >= s ? 4 : 0);
    }
    // precompute A addresses: zero per-step swizzle arithmetic beyond add+xor
    int baseA[2][5], xorA[2][5];
#pragma unroll
    for (int m = 0; m < 2; ++m)
#pragma unroll
        for (int k = 0; k < 5; ++k) {
            int row = rowb[m] + k;
            baseA[m][k] = row * 192;
            xorA[m][k] = (row & 7) << 3;
        }
    const int lg8 = lg * 8;

    f32x4 acc[2][4];
    f32x4 zz = {0.f, 0.f, 0.f, 0.f};
#pragma unroll
    for (int m = 0; m < 2; ++m)
#pragma unroll
        for (int n = 0; n < 4; ++n) acc[m][n] = zz;

    auto loadA = [&](bf16x8(&dst)[2], int step) {
        const int k = step / 6, cib = step % 6;
#pragma unroll
        for (int m = 0; m < 2; ++m)
            dst[m] = *(const bf16x8*)(xs + baseA[m][k] + ((cib * 32 + lg8) ^ xorA[m][k]));
    };
    auto domfma = [&](bf16x8(&A)[2], bf16x8(&B)[4]) {
#pragma unroll
        for (int m = 0; m < 2; ++m)
#pragma unroll
            for (int n = 0; n < 4; ++n)
                acc[m][n] = __builtin_amdgcn_mfma_f32_16x16x32_bf16(A[m], B[n], acc[m][n], 0, 0, 0);
    };

    loadA(aE, 0);
#pragma unroll
    for (int sp = 0; sp < 15; ++sp) {
        loadA(aO, 2 * sp + 1);
        domfma(aE, bE);                                    // step 2sp
        if (sp < 14) { loadA(aE, 2 * sp + 2); loadB(bE, 2 * sp + 2); }
        domfma(aO, bO);                                    // step 2sp+1
        if (sp < 14) loadB(bO, 2 * sp + 3);
    }

    float bias[4];
    const float* bb1 = b1 + (size_t)nb4 * NCH + cot * 128 + wcol * 64 + lr;
#pragma unroll
    for (int n = 0; n < 4; ++n) bias[n] = bb1[n * 16];
    u16* hz = h + (size_t)z * NB * Lout * NCH;
#pragma unroll
    for (int m = 0; m < 2; ++m) {
#pragma unroll
        for (int rr = 0; rr < 4; ++rr) {
            int i = wrow * 32 + m * 16 + lg * 4 + rr;
            if (i < rowsValid) {
                int cross = (i >= s) ? 1 : 0;
                int bb = b0 + cross;
                int tt = cross ? i - s : t00 + i;
                u16* dst = hz + ((size_t)bb * Lout + tt) * NCH + cot * 128 + wcol * 64 + lr;
#pragma unroll
                for (int n = 0; n < 4; ++n) {
                    float v = acc[m][n][rr] + bias[n];
                    v = v > 0.f ? v : 0.01f * v;
                    dst[n * 16] = f2bf(v);
                }
            }
        }
    }
}

// ---------- conv2 MFMA: 128x192 block, 512 thr (2x4 waves of 64x48) ----------
// cc loop UNROLLED so the B/A ring indices are compile-time (rule #20)
__global__ __launch_bounds__(512) void conv2m(
    u16* __restrict__ bufb, u16* __restrict__ dbufb, u16* __restrict__ cbufb,
    const u16* __restrict__ W2f, const float* __restrict__ b2,
    const u16* __restrict__ h, int lvl, int stage) {
    const int L = 512 >> lvl, nodes = 1 << lvl, Lout = L + 2;
    const int tid = threadIdx.x;
    const int nM = (NB * L) >> 7;
    const int wg = xcd_swz(blockIdx.x, gridDim.x);
    const int z = wg / nM;
    const int mt = wg - z * nM;
    const int g_node = z & (nodes - 1);
    const int br = z >> lvl;
    const int nb4 = NODE_IDX[lvl][g_node] * 4 + (stage ? 2 + br : br);
    const int r0 = mt * 128;
    const int b = r0 >> (9 - lvl);
    const int t0 = r0 & (L - 1);

    __shared__ u16 xs[130 * 192];
    const u16* hz = h + ((size_t)z * NB + b) * Lout * NCH;

    const int lane = tid & 63, w = tid >> 6;
    const int wrow = w >> 2, wcol = w & 3;
    const int lr = lane & 15, lg = lane >> 4;
    const u16* wf = W2f + ((size_t)nb4 * 72 * 12 + wcol * 3) * 512 + lane * 8;

    auto kkb_of = [](int st) {
        int cc = st / 18, sp = st % 18;
        return (sp / 6) * 24 + cc * 6 + (sp % 6);
    };
    bf16x8 Bb[4][3], Ab[2][4];
    auto loadB = [&](bf16x8(&dst)[3], int st) {
        const size_t kb = (size_t)kkb_of(st) * 12 * 512;
#pragma unroll
        for (int n = 0; n < 3; ++n)
            dst[n] = *(const bf16x8*)(wf + kb + (size_t)n * 512);
    };
    auto loadA = [&](bf16x8(&dst)[4], int sp) {
        const int k = sp / 6, cj = sp % 6;
#pragma unroll
        for (int m = 0; m < 4; ++m) {
            int row = wrow * 64 + m * 16 + lr + k;
            dst[m] = *(const bf16x8*)(xs + row * 192 + ((cj * 32 + lg * 8) ^ ((row & 7) << 3)));
        }
    };
    loadB(Bb[0], 0);
    loadB(Bb[1], 1);
    loadB(Bb[2], 2);

    f32x4 acc[4][3];
    f32x4 zz = {0.f, 0.f, 0.f, 0.f};
#pragma unroll
    for (int m = 0; m < 4; ++m)
#pragma unroll
        for (int n = 0; n < 3; ++n) acc[m][n] = zz;

#pragma unroll
    for (int cc = 0; cc < 4; ++cc) {
        __syncthreads();
        for (int ch = tid; ch < 130 * 24; ch += 512) {
            int j = ch / 24, c8 = ch % 24;
            *(uint4*)(xs + j * 192 + ((c8 * 8) ^ ((j & 7) << 3))) =
                *(const uint4*)(hz + (size_t)(t0 + j) * NCH + cc * 192 + c8 * 8);
        }
        __syncthreads();
        loadA(Ab[0], 0);
#pragma unroll
        for (int sp = 0; sp < 18; ++sp) {
            int st = cc * 18 + sp;
            if (st + 3 < 72) loadB(Bb[(st + 3) & 3], st + 3);
            if (sp + 1 < 18) loadA(Ab[(sp + 1) & 1], sp + 1);
#pragma unroll
            for (int m = 0; m < 4; ++m)
#pragma unroll
                for (int n = 0; n < 3; ++n)
                    acc[m][n] = __builtin_amdgcn_mfma_f32_16x16x32_bf16(
                        Ab[sp & 1][m], Bb[st & 3][n], acc[m][n], 0, 0, 0);
        }
    }

    float bias[3];
    const float* bb2 = b2 + (size_t)nb4 * ND + wcol * 48 + lr;
#pragma unroll
    for (int n = 0; n < 3; ++n) bias[n] = bb2[n * 16];

    const int tstr = 2 * nodes;
    if (stage == 0) {
        const int mo = g_node + (br == 0 ? nodes : 0);
        const u16* mult = bufb + ((size_t)b * NT + mo) * ND;
        u16* dst = (br == 0 ? dbufb : cbufb) + ((size_t)g_node * NB + b) * (size_t)L * ND;
#pragma unroll
        for (int m = 0; m < 4; ++m) {
#pragma unroll
            for (int rr = 0; rr < 4; ++rr) {
                int i = wrow * 64 + m * 16 + lg * 4 + rr;
                int t = t0 + i;
#pragma unroll
                for (int n = 0; n < 3; ++n) {
                    int co = wcol * 48 + n * 16 + lr;
                    float v = tanh_fast(acc[m][n][rr] + bias[n]);
                    float mlt = bf2f(mult[(size_t)t * tstr * ND + co]);
                    dst[(size_t)t * ND + co] = f2bf(mlt * __expf(v));
                }
            }
        }
    } else {
        const u16* other = (br == 0 ? cbufb : dbufb) + ((size_t)g_node * NB + b) * (size_t)L * ND;
        const int to = g_node + (br ? nodes : 0);
        u16* dst = bufb + ((size_t)b * NT + to) * ND;
#pragma unroll
        for (int m = 0; m < 4; ++m) {
#pragma unroll
            for (int rr = 0; rr < 4; ++rr) {
                int i = wrow * 64 + m * 16 + lg * 4 + rr;
                int t = t0 + i;
#pragma unroll
                for (int n = 0; n < 3; ++n) {
                    int co = wcol * 48 + n * 16 + lr;
                    float v = tanh_fast(acc[m][n][rr] + bias[n]);
                    float o = bf2f(other[(size_t)t * ND + co]);
                    dst[(size_t)t * tstr * ND + co] = f2bf(br == 0 ? o + v : o - v);
                }
            }
        }
    }
}

// ---------- build in2T[b][d][t] = bf16(buf + x) transposed ----------
__global__ __launch_bounds__(256) void mkin2T(const u16* __restrict__ bufb,
                                              const float* __restrict__ x,
                                              u16* __restrict__ in2T) {
    __shared__ u16 ls[64][72];
    const int b = blockIdx.z, t0 = blockIdx.y * 64, d0 = blockIdx.x * 64;
    const int tid = threadIdx.x;
#pragma unroll
    for (int it = 0; it < 2; ++it) {
        int idx = tid + it * 256;
        int c8 = idx >> 6, row = idx & 63;
        size_t base = ((size_t)b * NT + t0 + row) * ND + d0 + c8 * 8;
        uint4 vb = *(const uint4*)(bufb + base);
        float4 x1 = *(const float4*)(x + base);
        float4 x2 = *(const float4*)(x + base + 4);
        const u16* vs = (const u16*)&vb;
        ls[c8 * 8 + 0][row] = f2bf(bf2f(vs[0]) + x1.x);
        ls[c8 * 8 + 1][row] = f2bf(bf2f(vs[1]) + x1.y);
        ls[c8 * 8 + 2][row] = f2bf(bf2f(vs[2]) + x1.z);
        ls[c8 * 8 + 3][row] = f2bf(bf2f(vs[3]) + x1.w);
        ls[c8 * 8 + 4][row] = f2bf(bf2f(vs[4]) + x2.x);
        ls[c8 * 8 + 5][row] = f2bf(bf2f(vs[5]) + x2.y);
        ls[c8 * 8 + 6][row] = f2bf(bf2f(vs[6]) + x2.z);
        ls[c8 * 8 + 7][row] = f2bf(bf2f(vs[7]) + x2.w);
    }
    __syncthreads();
#pragma unroll
    for (int it = 0; it < 2; ++it) {
        int idx = tid + it * 256;
        int dl = idx >> 3, t8 = idx & 7;
        uint4 v = *(uint4*)&ls[dl][t8 * 8];
        *(uint4*)(in2T + ((size_t)b * ND + d0 + dl) * NT + t0 + t8 * 8) = v;
    }
}

// ---------- projection MFMA: out[b][o][d] = sum_t Wp[o][t]*(buf+x)[t][d] ----------
__global__ __launch_bounds__(256) void projm(const u16* __restrict__ in2T,
                                             const u16* __restrict__ Wpb,
                                             float* __restrict__ out) {
    const int b = blockIdx.y, ot = blockIdx.x;
    const int tid = threadIdx.x, lane = tid & 63, w = tid >> 6;
    const int lr = lane & 15, lg = lane >> 4;
    const u16* ap = Wpb + ((size_t)(ot * 32 + lr)) * NT + lg * 8;
    const u16* bp = in2T + ((size_t)b * ND + w * 48 + lr) * NT + lg * 8;

    f32x4 acc[2][3];
    f32x4 zz = {0.f, 0.f, 0.f, 0.f};
#pragma unroll
    for (int m = 0; m < 2; ++m)
#pragma unroll
        for (int n = 0; n < 3; ++n) acc[m][n] = zz;

    auto loadA = [&](bf16x8(&dst)[2], int kkb) {
#pragma unroll
        for (int m = 0; m < 2; ++m)
            dst[m] = *(const bf16x8*)(ap + (size_t)m * 16 * NT + kkb * 32);
    };
    auto loadB = [&](bf16x8(&dst)[3], int kkb) {
#pragma unroll
        for (int n = 0; n < 3; ++n)
            dst[n] = *(const bf16x8*)(bp + (size_t)n * 16 * NT + kkb * 32);
    };
    auto domfma = [&](bf16x8(&A)[2], bf16x8(&B)[3]) {
#pragma unroll
        for (int m = 0; m < 2; ++m)
#pragma unroll
            for (int n = 0; n < 3; ++n)
                acc[m][n] = __builtin_amdgcn_mfma_f32_16x16x32_bf16(A[m], B[n], acc[m][n], 0, 0, 0);
    };

    bf16x8 Ab[2][2], Bb[3][3];
    loadA(Ab[0], 0);
    loadB(Bb[0], 0);
    loadB(Bb[1], 1);
#pragma unroll
    for (int sp = 0; sp < 32; ++sp) {
        if (sp + 2 < 32) loadB(Bb[(sp + 2) % 3], sp + 2);
        if (sp + 1 < 32) loadA(Ab[(sp + 1) & 1], sp + 1);
        domfma(Ab[sp & 1], Bb[sp % 3]);
    }

#pragma unroll
    for (int m = 0; m < 2; ++m)
#pragma unroll
        for (int rr = 0; rr < 4; ++rr) {
            int o = ot * 32 + m * 16 + lg * 4 + rr;
#pragma unroll
            for (int n = 0; n < 3; ++n) {
                int d = w * 48 + n * 16 + lr;
                out[((size_t)b * NOUT + o) * ND + d] = acc[m][n][rr];
            }
        }
}

extern "C" void kernel_launch(void* const* d_in, const int* in_sizes, int n_in,
                              void* d_out, int out_size, void* d_ws, size_t ws_size,
                              hipStream_t stream) {
    const float* x = (const float*)d_in[0];
    const float* W1 = (const float*)d_in[1];
    const float* b1 = (const float*)d_in[2];
    const float* W2 = (const float*)d_in[3];
    const float* b2 = (const float*)d_in[4];
    const float* Wp = (const float*)d_in[5];
    float* out = (float*)d_out;

    char* wsb = (char*)d_ws;
    size_t off = 0;
    auto carve = [&](size_t bytes) {
        void* p = wsb + off;
        off += (bytes + 255) & ~(size_t)255;
        return p;
    };
    const size_t w1f_e = (size_t)28 * 30 * 48 * 512;
    const size_t w2f_e = (size_t)28 * 72 * 12 * 512;
    const size_t wpb_e = (size_t)NOUT * NT;
    const size_t buf_e = (size_t)NB * NT * ND;
    const size_t dc_e = (size_t)NB * 512 * ND;
    const size_t h_e = (size_t)1040 * NB * NCH;
    const size_t i2_e = (size_t)NB * ND * NT;

    u16* W1f = (u16*)carve(sizeof(u16) * w1f_e);
    u16* W2f = (u16*)carve(sizeof(u16) * w2f_e);
    u16* Wpb = (u16*)carve(sizeof(u16) * wpb_e);
    u16* bufb = (u16*)carve(sizeof(u16) * buf_e);
    u16* dbufb = (u16*)carve(sizeof(u16) * dc_e);
    u16* cbufb = (u16*)carve(sizeof(u16) * dc_e);
    u16* h = (u16*)carve(sizeof(u16) * h_e);
    u16* in2T = (u16*)carve(sizeof(u16) * i2_e);
    if (off > ws_size) return;

    cvt8<<<(int)(buf_e / 8 / 256), 256, 0, stream>>>(x, bufb, (int)(buf_e / 8));
    cvt8<<<(int)(wpb_e / 8 / 256), 256, 0, stream>>>(Wp, Wpb, (int)(wpb_e / 8));
    w1fk<<<28 * 24, 256, 0, stream>>>(W1, W1f);
    w2fk<<<28 * 12 * 2, 256, 0, stream>>>(W2, W2f);

    for (int lvl = 0; lvl < 3; ++lvl) {
        int L = 512 >> lvl, nodes = 1 << lvl, Lout = L + 2;
        int mT1 = (NB * Lout + 63) / 64;
        int nM = NB * L / 128;
        dim3 g1(6 * mT1 * 2 * nodes);
        dim3 g2(nM * 2 * nodes);
        conv1m<<<g1, 256, 0, stream>>>(bufb, dbufb, cbufb, W1f, b1, h, lvl, 0);
        conv2m<<<g2, 512, 0, stream>>>(bufb, dbufb, cbufb, W2f, b2, h, lvl, 0);
        conv1m<<<g1, 256, 0, stream>>>(bufb, dbufb, cbufb, W1f, b1, h, lvl, 1);
        conv2m<<<g2, 512, 0, stream>>>(bufb, dbufb, cbufb, W2f, b2, h, lvl, 1);
    }
    mkin2T<<<dim3(3, 16, NB), 256, 0, stream>>>(bufb, x, in2T);
    projm<<<dim3(16, NB), 256, 0, stream>>>(in2T, Wpb, out);
}